// Round 2
// baseline (1039.333 us; speedup 1.0000x reference)
//
#include <hip/hip_runtime.h>

#define NUM_BUCKETS 2000003ull
#define HASH_MULT   92821ull
#define SEQ         8192
#define NTOK        32768          // 4 * 8192
#define MDIM        1024
#define HDIM        64
#define G           64             // tokens per block

// Pre-kernel: bucket ids once (64-bit mod; don't redo per dim-wave).
__global__ __launch_bounds__(256) void hash_kernel(const int* __restrict__ ids,
                                                   int* __restrict__ hbuf) {
    int t = blockIdx.x * 256 + threadIdx.x;
    if (t >= NTOK) return;
    unsigned long long cur  = (unsigned long long)(unsigned int)ids[t];
    unsigned long long prev = ((t & (SEQ - 1)) == 0)
                                  ? 0ull
                                  : (unsigned long long)(unsigned int)ids[t - 1];
    hbuf[t] = (int)((prev * HASH_MULT + cur) % NUM_BUCKETS);
}

// Block = 1024 threads = all 1024 model dims; lane's W row lives in VGPRs.
// The 64 token-rows (16 KB) are staged into LDS with ONE fully-coalesced
// pass (thread i loads float4 #i), then read back per-token at a
// block-uniform address -> LDS broadcast (conflict-free), avoiding the
// R1 disease of per-lane VMEM address processing on duplicated addresses.
__global__ __launch_bounds__(1024, 4) void bigram_kernel(const int*   __restrict__ hbuf,
                                                         const float* __restrict__ table,
                                                         const float* __restrict__ W,
                                                         float*       __restrict__ out) {
    __shared__ float rows[G * HDIM];   // 64 rows x 256 B = 16 KB

    const int m = threadIdx.x;         // model dim owned by this lane

    // --- Stage: 64 rows, one float4 per thread (coalesced: 16 lanes = 256 B
    // contiguous per row; 4 rows per wave). Issued before the W loads so the
    // gather latency overlaps them.
    {
        const int r = m >> 4;          // row 0..63
        const int q = m & 15;          // float4 within row
        const int h = hbuf[blockIdx.x * G + r];
        const float4 v = *(const float4*)(table + (size_t)h * HDIM + q * 4);
        *(float4*)(&rows[r * HDIM + q * 4]) = v;
    }

    // W row for this dim: 16 float4 = 64 VGPRs, reused for all 64 tokens.
    float4 w[16];
    const float4* Wv = (const float4*)(W + (size_t)m * HDIM);
#pragma unroll
    for (int i = 0; i < 16; ++i) w[i] = Wv[i];

    __syncthreads();

    const size_t obase = (size_t)blockIdx.x * G * MDIM + m;
    for (int t = 0; t < G; ++t) {
        const float4* e = (const float4*)(&rows[t * HDIM]);  // block-uniform addr
        float4 acc = {0.f, 0.f, 0.f, 0.f};
#pragma unroll
        for (int k = 0; k < 16; ++k) {
            float4 ev = e[k];          // ds_read_b128, broadcast
            acc.x = fmaf(w[k].x, ev.x, acc.x);
            acc.y = fmaf(w[k].y, ev.y, acc.y);
            acc.z = fmaf(w[k].z, ev.z, acc.z);
            acc.w = fmaf(w[k].w, ev.w, acc.w);
        }
        out[obase + (size_t)t * MDIM] = (acc.x + acc.y) + (acc.z + acc.w);
    }
}

extern "C" void kernel_launch(void* const* d_in, const int* in_sizes, int n_in,
                              void* d_out, int out_size, void* d_ws, size_t ws_size,
                              hipStream_t stream) {
    const int*   ids   = (const int*)d_in[0];
    const float* table = (const float*)d_in[1];
    const float* W     = (const float*)d_in[2];
    float*       out   = (float*)d_out;
    int*         hbuf  = (int*)d_ws;   // 128 KB of scratch

    hash_kernel<<<NTOK / 256, 256, 0, stream>>>(ids, hbuf);
    bigram_kernel<<<NTOK / G, 1024, 0, stream>>>(hbuf, table, W, out);
}

// Round 3
// 952.819 us; speedup vs baseline: 1.0908x; 1.0908x over previous
//
#include <hip/hip_runtime.h>

#define NTOK 32768         // 4 * 8192 tokens
#define SEQ  8192
#define MDIM 1024
#define HDIM 64
#define TB   64            // tokens per block (= lanes of a wave)
#define LP   65            // LDS row pitch: bank=(65t+4k)%32=(t+4k)%32 -> worst 2-way (free)

// One fused kernel. Block = 256 threads = 4 waves sharing 64 tokens.
// lane = token: e-row resident in 64 VGPRs; W streamed via SCALAR loads
// (wave-uniform addresses -> s_load, K$/L2 path, no VALU/LDS cost);
// inner loop = pure v_fma_f32 at issue rate.
__global__ __launch_bounds__(256) void bigram_fused(const int*   __restrict__ ids,
                                                    const float* __restrict__ table,
                                                    const float* __restrict__ W,
                                                    float*       __restrict__ out) {
    __shared__ int   hsh[TB];
    __shared__ float rows[TB * LP];    // 64 rows, pitch 65 floats (16.6 KB)

    const int tid = threadIdx.x;
    const int t0  = blockIdx.x * TB;

    // --- 1. bucket ids (wave 0 only; 64-bit mod done once per token)
    if (tid < TB) {
        const int t = t0 + tid;
        unsigned long long cur  = (unsigned long long)(unsigned int)ids[t];
        unsigned long long prev = ((t & (SEQ - 1)) == 0)
                                      ? 0ull
                                      : (unsigned long long)(unsigned int)ids[t - 1];
        hsh[tid] = (int)((prev * 92821ull + cur) % 2000003ull);
    }
    __syncthreads();

    // --- 2. stage 64 embedding rows (16 KB) into padded LDS, fully coalesced:
    // 16 consecutive threads read 16 consecutive float4 = 256 B of one row.
    #pragma unroll
    for (int j = 0; j < 4; ++j) {
        const int idx = j * 256 + tid;           // float4 slot 0..1023
        const int r = idx >> 4, q = idx & 15;
        const float4 v = *(const float4*)(table + (size_t)hsh[r] * HDIM + q * 4);
        *(float4*)(&rows[r * LP + q * 4]) = v;
    }
    __syncthreads();

    // --- 3. lane t pulls token t's full row into registers (pad-65 -> ~conflict-free)
    const int lane = tid & 63;
    float4 e[16];
    #pragma unroll
    for (int k = 0; k < 16; ++k)
        e[k] = *(const float4*)(&rows[lane * LP + k * 4]);

    // --- 4. m-sweep: wave w owns dims [256w, 256w+256). All W addresses are
    // wave-uniform (wid forced scalar) -> compiler emits s_load for W.
    const int    wid = __builtin_amdgcn_readfirstlane(tid >> 6);
    const float* Wb  = W + (size_t)wid * 256 * HDIM;
    float*       ob  = out + (size_t)(t0 + lane) * MDIM + wid * 256;

    for (int m4 = 0; m4 < 64; ++m4) {
        float4 acc;
        #pragma unroll
        for (int mm = 0; mm < 4; ++mm) {
            const float* wr = Wb + (m4 * 4 + mm) * HDIM;
            float s0 = 0.f, s1 = 0.f, s2 = 0.f, s3 = 0.f;
            #pragma unroll
            for (int k = 0; k < 16; ++k) {
                s0 = fmaf(wr[k * 4 + 0], e[k].x, s0);
                s1 = fmaf(wr[k * 4 + 1], e[k].y, s1);
                s2 = fmaf(wr[k * 4 + 2], e[k].z, s2);
                s3 = fmaf(wr[k * 4 + 3], e[k].w, s3);
            }
            (&acc.x)[mm] = (s0 + s1) + (s2 + s3);
        }
        *(float4*)(ob + m4 * 4) = acc;   // 16 B/lane; L2 merges into full lines
    }
}

extern "C" void kernel_launch(void* const* d_in, const int* in_sizes, int n_in,
                              void* d_out, int out_size, void* d_ws, size_t ws_size,
                              hipStream_t stream) {
    const int*   ids   = (const int*)d_in[0];
    const float* table = (const float*)d_in[1];
    const float* W     = (const float*)d_in[2];
    float*       out   = (float*)d_out;

    bigram_fused<<<NTOK / TB, 256, 0, stream>>>(ids, table, W, out);
}